// Round 6
// baseline (147.582 us; speedup 1.0000x reference)
//
#include <hip/hip_runtime.h>

// out = mean_i( rank_of_diag(cos_sim(x1,x2))_i < nper ), nper = S/100+1.
// rank_i = #{ j != i : dot(x1_i,x2_j)*inv||x2_j|| > dot(x1_i,x2_i)*inv||x2_i|| }
// GEMM via fp16x3 (Markidis split) MFMA: x=hi+lo; hi*hi + hi*lo + lo*hi.
// Dropped lo*lo ~2^-22 rel/term -> dot err ~3e-6 << 4.5e-3 order-stat spacing.
//
// R6: 256x256 LDS-resident tile (m201-class geometry, simplified for K=128).
// 512 thr / 8 waves (2Mx4N), wave tile 128x64, acc[4][2]. BK=32 chunks,
// double-buffered 2x64KB LDS, staged via global_load_lds identity-DMA from
// the fragment-major planes (contiguous spans, no ds_write, no conversion).
// One __syncthreads per chunk (4 total); stage issued at phase START so the
// barrier's vmcnt drain lands after ~3000 cyc of MFMA. Global traffic
// 1GB -> 256MB vs R4/R5 (intra-block reuse restored).
//
// Fragment-major plane layout (per plane, halves):
//   addr(row,k) = (row>>5)*4096 + ((k>>5)*2 + ((k>>4)&1))*512
//               + ((k>>3)&1)*256 + (row&31)*8 + (k&7)
// -> 32-row x 16-half fragment = contiguous 1KB, lane reads 16B at +lane*8.
// -> k-chunk of 32 for one rowgroup = contiguous 2KB at rg*4096 + c*1024.

#define KDIM 128

typedef _Float16 half8 __attribute__((ext_vector_type(8)));
typedef float floatx16 __attribute__((ext_vector_type(16)));

static __device__ __forceinline__ void gload16(const void* g, void* l)
{
    __builtin_amdgcn_global_load_lds(
        (__attribute__((address_space(1))) void*)(g),
        (__attribute__((address_space(3))) void*)(l),
        16, 0, 0);
}

// ---------- Kernel A: 1/||x2||, diag threshold, zero counters, fragment-major fp16 planes ----------
__global__ __launch_bounds__(256) void prep_kernel(
    const float* __restrict__ x1, const float* __restrict__ x2,
    float* __restrict__ invn, float* __restrict__ thr,
    int* __restrict__ row_count,
    unsigned* __restrict__ x1h, unsigned* __restrict__ x1l,
    unsigned* __restrict__ x2h, unsigned* __restrict__ x2l,
    int B, int S, int wplanes)
{
    const int wave = threadIdx.x >> 6;
    const int lane = threadIdx.x & 63;
    const int row = blockIdx.x * 4 + wave;
    if (row >= S && row >= B) return;

    float s22 = 0.f, s12 = 0.f;
    float2 a = make_float2(0.f, 0.f), b = make_float2(0.f, 0.f);
    if (row < B) a = ((const float2*)&x1[(size_t)row * KDIM])[lane];
    if (row < S) {
        b = ((const float2*)&x2[(size_t)row * KDIM])[lane];
        s22 = fmaf(b.x, b.x, b.y * b.y);
        s12 = fmaf(a.x, b.x, a.y * b.y);
    }

    if (wplanes) {
        // k = 2*lane, pair (k,k+1) shares one u32 slot.
        const int iu = (row >> 5) * 2048
                     + ((lane >> 4) * 2 + ((lane >> 3) & 1)) * 256
                     + ((lane >> 2) & 1) * 128
                     + (row & 31) * 4 + (lane & 3);
        if (row < B) {
            union { _Float16 h[2]; unsigned u; } hh, ll;
            hh.h[0] = (_Float16)a.x; ll.h[0] = (_Float16)(a.x - (float)hh.h[0]);
            hh.h[1] = (_Float16)a.y; ll.h[1] = (_Float16)(a.y - (float)hh.h[1]);
            x1h[iu] = hh.u;
            x1l[iu] = ll.u;
        }
        if (row < S) {
            union { _Float16 h[2]; unsigned u; } hh, ll;
            hh.h[0] = (_Float16)b.x; ll.h[0] = (_Float16)(b.x - (float)hh.h[0]);
            hh.h[1] = (_Float16)b.y; ll.h[1] = (_Float16)(b.y - (float)hh.h[1]);
            x2h[iu] = hh.u;
            x2l[iu] = ll.u;
        }
    }

    #pragma unroll
    for (int m = 32; m > 0; m >>= 1) {
        s22 += __shfl_xor(s22, m);
        s12 += __shfl_xor(s12, m);
    }
    if (lane == 0) {
        if (row < S) {
            float iv = rsqrtf(s22);
            invn[row] = iv;
            if (row < B) thr[row] = s12 * iv;
        }
        if (row < B) row_count[row] = 0;
    }
}

// ---------- Kernel B (fast): 256x256 DMA-staged fp16x3 MFMA GEMM + compare-count ----------
__global__ __launch_bounds__(512, 2) void count_kernel_fast(
    const _Float16* __restrict__ x1h, const _Float16* __restrict__ x1l,
    const _Float16* __restrict__ x2h, const _Float16* __restrict__ x2l,
    const float* __restrict__ invn, const float* __restrict__ thr,
    int* __restrict__ row_count, int nbx, int nby)
{
    // [buf][plane(hi/lo)][rg*1024 + ks2*512 + fr*8 + j] : 64KB per buf, 128KB
    __shared__ __align__(16) _Float16 sA[2][2][8192];
    __shared__ __align__(16) _Float16 sB[2][2][8192];
    __shared__ float s_thr[256], s_invn[256];
    __shared__ int cnt_s[256];

    const int tid  = threadIdx.x;
    const int wave = tid >> 6;
    const int lane = tid & 63;

    // ---- XCD band swizzle (1 block/CU; harmless if mapping drifts) ----
    const int wg = blockIdx.x;
    int bx, by;
    if ((nby & 7) == 0) {
        const int rpx = nby >> 3;
        by = (wg & 7) * rpx + ((wg >> 3) % rpx);
        bx = (wg >> 3) / rpx;
    } else {
        by = wg / nbx;
        bx = wg - by * nbx;
    }
    const int row0 = by * 256;
    const int col0 = bx * 256;
    const int wr = (wave >> 2) * 128;   // M-wave: rows [wr, wr+128)
    const int wc = (wave & 3) * 64;     // N-wave: cols [wc, wc+64)
    const int arg = wr >> 5;            // A rowgroup base (0 or 4)
    const int brg = wc >> 5;            // B rowgroup base (0,2,4,6)
    const int lane8 = lane * 8;

    const _Float16* pA0 = x1h + (size_t)(row0 >> 5) * 4096;
    const _Float16* pA1 = x1l + (size_t)(row0 >> 5) * 4096;
    const _Float16* pB0 = x2h + (size_t)(col0 >> 5) * 4096;
    const _Float16* pB1 = x2l + (size_t)(col0 >> 5) * 4096;

    // per-thread staging slots: o1/o2 are wave-uniform-block + lane*8 halves,
    // satisfying global_load_lds's (uniform base + lane*16B) LDS-dest rule;
    // global side is the same flat offset remapped to (rg, chunk) spans.
    const int o1 = tid * 8;             // [0, 4096)
    const int o2 = o1 + 4096;           // [4096, 8192)
    const int g1base = ((o1 >> 10) << 12) + (o1 & 1023);
    const int g2base = ((o2 >> 10) << 12) + (o2 & 1023);

#define STAGE(c, buf)                                                   \
    do {                                                                \
        const int g1 = g1base + (c) * 1024;                             \
        const int g2 = g2base + (c) * 1024;                             \
        gload16(pA0 + g1, &sA[buf][0][o1]);                             \
        gload16(pA0 + g2, &sA[buf][0][o2]);                             \
        gload16(pA1 + g1, &sA[buf][1][o1]);                             \
        gload16(pA1 + g2, &sA[buf][1][o2]);                             \
        gload16(pB0 + g1, &sB[buf][0][o1]);                             \
        gload16(pB0 + g2, &sB[buf][0][o2]);                             \
        gload16(pB1 + g1, &sB[buf][1][o1]);                             \
        gload16(pB1 + g2, &sB[buf][1][o2]);                             \
    } while (0)

    floatx16 acc[4][2];
    #pragma unroll
    for (int a = 0; a < 4; a++)
        #pragma unroll
        for (int b = 0; b < 2; b++)
            #pragma unroll
            for (int i = 0; i < 16; i++) acc[a][b][i] = 0.f;

    STAGE(0, 0);
    __syncthreads();                    // chunk0 landed

    #pragma unroll
    for (int t = 0; t < 4; t++) {
        const int buf = t & 1;          // compile-time after unroll
        if (t < 3) STAGE(t + 1, buf ^ 1);   // in flight under this chunk's MFMAs

        #pragma unroll
        for (int ks2 = 0; ks2 < 2; ks2++) {
            const int so = ks2 * 512 + lane8;
            half8 ah[4], al[4], bh[2], bl[2];
            #pragma unroll
            for (int m = 0; m < 4; m++) {
                ah[m] = *(const half8*)&sA[buf][0][(arg + m) * 1024 + so];
                al[m] = *(const half8*)&sA[buf][1][(arg + m) * 1024 + so];
            }
            #pragma unroll
            for (int n = 0; n < 2; n++) {
                bh[n] = *(const half8*)&sB[buf][0][(brg + n) * 1024 + so];
                bl[n] = *(const half8*)&sB[buf][1][(brg + n) * 1024 + so];
            }
            #pragma unroll
            for (int mt = 0; mt < 4; mt++)
                #pragma unroll
                for (int nt = 0; nt < 2; nt++) {
                    acc[mt][nt] = __builtin_amdgcn_mfma_f32_32x32x16_f16(al[mt], bh[nt], acc[mt][nt], 0, 0, 0);
                    acc[mt][nt] = __builtin_amdgcn_mfma_f32_32x32x16_f16(ah[mt], bl[nt], acc[mt][nt], 0, 0, 0);
                    acc[mt][nt] = __builtin_amdgcn_mfma_f32_32x32x16_f16(ah[mt], bh[nt], acc[mt][nt], 0, 0, 0);
                }
        }
        __syncthreads();                // staged buffer ready; old buffer free
    }
#undef STAGE

    // ---- epilogue: normalize, compare vs diag threshold, ballot-count ----
    if (tid < 256) {
        cnt_s[tid]  = 0;
        s_thr[tid]  = thr[row0 + tid];
        s_invn[tid] = invn[col0 + tid];
    }
    __syncthreads();

    // C/D layout (32x32): col = lane&31, row = (reg&3) + 8*(reg>>2) + 4*(lane>>5)
    const int cm = lane & 31;
    const int hw = lane >> 5;
    const float iv0 = s_invn[wc + cm];
    const float iv1 = s_invn[wc + 32 + cm];
    const int gc0 = col0 + wc + cm;
    const int gc1 = gc0 + 32;

    #pragma unroll
    for (int mt = 0; mt < 4; mt++) {
        #pragma unroll
        for (int reg = 0; reg < 16; reg++) {
            const int rbase = wr + mt * 32 + (reg & 3) + 8 * (reg >> 2);
            const int rloc  = rbase + 4 * hw;
            const int grow  = row0 + rloc;
            const float t   = s_thr[rloc];
            const bool p0 = (acc[mt][0][reg] * iv0 > t) && (gc0 != grow);
            const bool p1 = (acc[mt][1][reg] * iv1 > t) && (gc1 != grow);
            const unsigned long long b0 = __ballot(p0);
            const unsigned long long b1 = __ballot(p1);
            if (lane == 0) {
                const int clo = __popcll(b0 & 0xffffffffULL) + __popcll(b1 & 0xffffffffULL);
                if (clo) atomicAdd(&cnt_s[rbase], clo);
            } else if (lane == 32) {
                const int chi = __popcll(b0 >> 32) + __popcll(b1 >> 32);
                if (chi) atomicAdd(&cnt_s[rbase + 4], chi);
            }
        }
    }
    __syncthreads();
    if (tid < 256) {
        const int v = cnt_s[tid];
        if (v) atomicAdd(&row_count[row0 + tid], v);
    }
}

// ---------- Kernel B (fallback, proven): in-kernel conversion path ----------
__global__ __launch_bounds__(256) void count_kernel_conv(
    const float* __restrict__ x1, const float* __restrict__ x2,
    const float* __restrict__ invn, const float* __restrict__ thr,
    int* __restrict__ row_count)
{
    __shared__ __align__(16) _Float16 As_hi[4096], As_lo[4096];
    __shared__ __align__(16) _Float16 Bs_hi[4096], Bs_lo[4096];
    __shared__ float s_thr[128], s_invn[128];
    __shared__ int cnt_s[128];

    const int tid  = threadIdx.x;
    const int wave = tid >> 6;
    const int lane = tid & 63;
    const int row0 = blockIdx.y * 128;
    const int col0 = blockIdx.x * 128;
    const int wr = (wave >> 1) * 64;
    const int wc = (wave & 1) * 64;

    if (tid < 128) {
        cnt_s[tid]  = 0;
        s_thr[tid]  = thr[row0 + tid];
        s_invn[tid] = invn[col0 + tid];
    }

    floatx16 acc[2][2];
    #pragma unroll
    for (int a = 0; a < 2; a++)
        #pragma unroll
        for (int b = 0; b < 2; b++)
            #pragma unroll
            for (int i = 0; i < 16; i++) acc[a][b][i] = 0.f;

    const int sr   = tid >> 1;
    const int sks2 = tid & 1;
    const int wbase = ((sr >> 5) * 2 + sks2) * 512 + (sr & 31) * 8;
    const size_t ga = (size_t)(row0 + sr) * KDIM + sks2 * 16;
    const size_t gb = (size_t)(col0 + sr) * KDIM + sks2 * 16;

    const int wrg = wr >> 5;
    const int wcg = wc >> 5;
    const int lane8 = lane * 8;

    for (int kc = 0; kc < KDIM; kc += 32) {
        __syncthreads();
        {
            const float* p = &x1[ga + kc];
            float v[16];
            *(float4*)&v[0]  = *(const float4*)(p);
            *(float4*)&v[4]  = *(const float4*)(p + 4);
            *(float4*)&v[8]  = *(const float4*)(p + 8);
            *(float4*)&v[12] = *(const float4*)(p + 12);
            half8 h0, h1, l0, l1;
            #pragma unroll
            for (int i = 0; i < 8; i++) {
                _Float16 h = (_Float16)v[i];
                h0[i] = h; l0[i] = (_Float16)(v[i] - (float)h);
                _Float16 g = (_Float16)v[i + 8];
                h1[i] = g; l1[i] = (_Float16)(v[i + 8] - (float)g);
            }
            *(half8*)&As_hi[wbase]       = h0;
            *(half8*)&As_hi[wbase + 256] = h1;
            *(half8*)&As_lo[wbase]       = l0;
            *(half8*)&As_lo[wbase + 256] = l1;
        }
        {
            const float* p = &x2[gb + kc];
            float v[16];
            *(float4*)&v[0]  = *(const float4*)(p);
            *(float4*)&v[4]  = *(const float4*)(p + 4);
            *(float4*)&v[8]  = *(const float4*)(p + 8);
            *(float4*)&v[12] = *(const float4*)(p + 12);
            half8 h0, h1, l0, l1;
            #pragma unroll
            for (int i = 0; i < 8; i++) {
                _Float16 h = (_Float16)v[i];
                h0[i] = h; l0[i] = (_Float16)(v[i] - (float)h);
                _Float16 g = (_Float16)v[i + 8];
                h1[i] = g; l1[i] = (_Float16)(v[i + 8] - (float)g);
            }
            *(half8*)&Bs_hi[wbase]       = h0;
            *(half8*)&Bs_hi[wbase + 256] = h1;
            *(half8*)&Bs_lo[wbase]       = l0;
            *(half8*)&Bs_lo[wbase + 256] = l1;
        }
        __syncthreads();

        #pragma unroll
        for (int ks2 = 0; ks2 < 2; ks2++) {
            half8 ah[2], al[2], bh[2], bl[2];
            #pragma unroll
            for (int t = 0; t < 2; t++) {
                const int oa = ((wrg + t) * 2 + ks2) * 512 + lane8;
                ah[t] = *(const half8*)&As_hi[oa];
                al[t] = *(const half8*)&As_lo[oa];
                const int ob = ((wcg + t) * 2 + ks2) * 512 + lane8;
                bh[t] = *(const half8*)&Bs_hi[ob];
                bl[t] = *(const half8*)&Bs_lo[ob];
            }
            #pragma unroll
            for (int mt = 0; mt < 2; mt++)
                #pragma unroll
                for (int nt = 0; nt < 2; nt++) {
                    acc[mt][nt] = __builtin_amdgcn_mfma_f32_32x32x16_f16(al[mt], bh[nt], acc[mt][nt], 0, 0, 0);
                    acc[mt][nt] = __builtin_amdgcn_mfma_f32_32x32x16_f16(ah[mt], bl[nt], acc[mt][nt], 0, 0, 0);
                    acc[mt][nt] = __builtin_amdgcn_mfma_f32_32x32x16_f16(ah[mt], bh[nt], acc[mt][nt], 0, 0, 0);
                }
        }
    }

    const int cm = lane & 31;
    const int hw = lane >> 5;
    const float iv0 = s_invn[wc + cm];
    const float iv1 = s_invn[wc + 32 + cm];
    const int gc0 = col0 + wc + cm;
    const int gc1 = gc0 + 32;

    #pragma unroll
    for (int mt = 0; mt < 2; mt++) {
        #pragma unroll
        for (int reg = 0; reg < 16; reg++) {
            const int rbase = wr + mt * 32 + (reg & 3) + 8 * (reg >> 2);
            const int rloc  = rbase + 4 * hw;
            const int grow  = row0 + rloc;
            const float t   = s_thr[rloc];
            const bool p0 = (acc[mt][0][reg] * iv0 > t) && (gc0 != grow);
            const bool p1 = (acc[mt][1][reg] * iv1 > t) && (gc1 != grow);
            const unsigned long long b0 = __ballot(p0);
            const unsigned long long b1 = __ballot(p1);
            if (lane == 0) {
                const int clo = __popcll(b0 & 0xffffffffULL) + __popcll(b1 & 0xffffffffULL);
                if (clo) atomicAdd(&cnt_s[rbase], clo);
            } else if (lane == 32) {
                const int chi = __popcll(b0 >> 32) + __popcll(b1 >> 32);
                if (chi) atomicAdd(&cnt_s[rbase + 4], chi);
            }
        }
    }
    __syncthreads();
    if (tid < 128) {
        const int v = cnt_s[tid];
        if (v) atomicAdd(&row_count[row0 + tid], v);
    }
}

// ---------- Kernel C: final reduction ----------
__global__ __launch_bounds__(1024) void finalize_kernel(
    const int* __restrict__ row_count, float* __restrict__ out, int B, int nper)
{
    __shared__ int wsum[16];
    const int t = threadIdx.x;
    int c = 0;
    for (int i = t; i < B; i += 1024) c += (row_count[i] < nper) ? 1 : 0;
    #pragma unroll
    for (int m = 32; m > 0; m >>= 1) c += __shfl_xor(c, m);
    if ((t & 63) == 0) wsum[t >> 6] = c;
    __syncthreads();
    if (t == 0) {
        int tot = 0;
        #pragma unroll
        for (int w = 0; w < 16; w++) tot += wsum[w];
        out[0] = (float)tot / (float)B;
    }
}

extern "C" void kernel_launch(void* const* d_in, const int* in_sizes, int n_in,
                              void* d_out, int out_size, void* d_ws, size_t ws_size,
                              hipStream_t stream)
{
    const float* x1 = (const float*)d_in[0];
    const float* x2 = (const float*)d_in[1];
    const int B = in_sizes[0] / KDIM;     // 8192
    const int S = in_sizes[1] / KDIM;     // 8192
    const int nper = S / 100 + 1;         // 82

    float* invn      = (float*)d_ws;
    float* thr       = invn + S;
    int*   row_count = (int*)(thr + B);

    uintptr_t ap = ((uintptr_t)(row_count + B) + 15) & ~(uintptr_t)15;
    _Float16* x1h = (_Float16*)ap;
    _Float16* x1l = x1h + (size_t)B * KDIM;
    _Float16* x2h = x1l + (size_t)B * KDIM;
    _Float16* x2l = x2h + (size_t)S * KDIM;
    const size_t need = (size_t)((char*)(x2l + (size_t)S * KDIM) - (char*)d_ws);
    // fast path: ws for planes + 256-divisible dims (256x256 tiles)
    const int fast = (ws_size >= need && (B % 256) == 0 && (S % 256) == 0) ? 1 : 0;

    const int mx = (B > S) ? B : S;
    prep_kernel<<<(mx + 3) / 4, 256, 0, stream>>>(
        x1, x2, invn, thr, row_count,
        (unsigned*)x1h, (unsigned*)x1l, (unsigned*)x2h, (unsigned*)x2l,
        B, S, fast);

    if (fast) {
        const int nbx = S / 256, nby = B / 256;
        count_kernel_fast<<<nbx * nby, 512, 0, stream>>>(
            x1h, x1l, x2h, x2l, invn, thr, row_count, nbx, nby);
    } else {
        dim3 grid(S / 128, B / 128);
        count_kernel_conv<<<grid, 256, 0, stream>>>(x1, x2, invn, thr, row_count);
    }

    finalize_kernel<<<1, 1024, 0, stream>>>(row_count, (float*)d_out, B, nper);
}